// Round 4
// baseline (100.045 us; speedup 1.0000x reference)
//
#include <hip/hip_runtime.h>
#include <math.h>

#define DD  256
#define LKK 512
#define LQQ 256
#define BB  4

constexpr float TWO_LOG2E = 2.8853900817779268f;  // 2*log2(e)
constexpr float LOG2E     = 1.4426950408889634f;

__device__ __forceinline__ float fast_rcp(float x)  { return __builtin_amdgcn_rcpf(x); }
__device__ __forceinline__ float fast_exp2(float x) { return __builtin_amdgcn_exp2f(x); }

#define COMP(v,u) ((u)==0?(v).x:(u)==1?(v).y:(u)==2?(v).z:(v).w)

// EaT[b][e][k] = exp(2 * key[b,k,:] . W1[e,:])  (d-major / transposed)
// Eb [b*LQ+q][e] = exp(2 * query[b,q,:] . W2[e,:])  (row-major)
// Software-pipelined: next k-tile loads issue before the current consume loop.
__global__ __launch_bounds__(256) void gemm_expk2(const float* __restrict__ key,
                                                  const float* __restrict__ query,
                                                  const float* __restrict__ W1,
                                                  const float* __restrict__ W2,
                                                  float* __restrict__ EaT,
                                                  float* __restrict__ Eb) {
  __shared__ float Xs[16][36];
  __shared__ float Ws[16][68];
  const int tid = threadIdx.x;
  const bool isK = blockIdx.x < (BB * LKK / 32);
  const float* __restrict__ X = isK ? key : query;
  const float* __restrict__ W = isK ? W1 : W2;
  const int m0 = (isK ? blockIdx.x : blockIdx.x - BB * LKK / 32) * 32;
  const int e0 = blockIdx.y * 64;

  const int r0 = (tid >> 4) << 1;   // 0..30
  const int c0 = (tid & 15) << 2;   // 0..60
  const int xr = tid >> 3, xc = (tid & 7) << 1;
  const int wr = tid >> 2, wc = (tid & 3) << 2;

  float2 xv = *(const float2*)&X[(m0 + xr) * DD + xc];
  float4 wv = *(const float4*)&W[(e0 + wr) * DD + wc];

  float acc[2][4] = {};
  for (int k0 = 0; k0 < DD; k0 += 16) {
    __syncthreads();
    Xs[xc][xr] = xv.x; Xs[xc + 1][xr] = xv.y;
    Ws[wc][wr] = wv.x; Ws[wc + 1][wr] = wv.y; Ws[wc + 2][wr] = wv.z; Ws[wc + 3][wr] = wv.w;
    __syncthreads();
    if (k0 + 16 < DD) {  // prefetch next tile; latency hides under the 128 FMAs below
      xv = *(const float2*)&X[(m0 + xr) * DD + k0 + 16 + xc];
      wv = *(const float4*)&W[(e0 + wr) * DD + k0 + 16 + wc];
    }
#pragma unroll
    for (int k = 0; k < 16; ++k) {
      const float2 a  = *(const float2*)&Xs[k][r0];
      const float4 bq = *(const float4*)&Ws[k][c0];
      acc[0][0] = fmaf(a.x, bq.x, acc[0][0]); acc[0][1] = fmaf(a.x, bq.y, acc[0][1]);
      acc[0][2] = fmaf(a.x, bq.z, acc[0][2]); acc[0][3] = fmaf(a.x, bq.w, acc[0][3]);
      acc[1][0] = fmaf(a.y, bq.x, acc[1][0]); acc[1][1] = fmaf(a.y, bq.y, acc[1][1]);
      acc[1][2] = fmaf(a.y, bq.z, acc[1][2]); acc[1][3] = fmaf(a.y, bq.w, acc[1][3]);
    }
  }
  if (isK) {
    const int b = m0 >> 9;
    const int kloc = (m0 & 511) + r0;
#pragma unroll
    for (int j = 0; j < 4; ++j) {
      float2 o;
      o.x = fast_exp2(acc[0][j] * TWO_LOG2E);
      o.y = fast_exp2(acc[1][j] * TWO_LOG2E);
      *(float2*)&EaT[b * (DD * LKK) + (e0 + c0 + j) * LKK + kloc] = o;
    }
  } else {
#pragma unroll
    for (int i = 0; i < 2; ++i) {
      float4 o;
      o.x = fast_exp2(acc[i][0] * TWO_LOG2E);
      o.y = fast_exp2(acc[i][1] * TWO_LOG2E);
      o.z = fast_exp2(acc[i][2] * TWO_LOG2E);
      o.w = fast_exp2(acc[i][3] * TWO_LOG2E);
      *(float4*)&Eb[(m0 + r0 + i) * DD + e0 + c0] = o;
    }
  }
}

// One block per (b, 4 q-rows): 256 blocks x 1024 threads (16 waves/CU, 4/SIMD).
// Scores: thread = (d-eighth, 4 k, all 4 q); two-pass LDS reduce keeps scratch 33KB.
__global__ __launch_bounds__(1024) void attn_fused(const float* __restrict__ EaT,
                                                   const float* __restrict__ Eb,
                                                   const float* __restrict__ vvec,
                                                   const float* __restrict__ value,
                                                   const int* __restrict__ mask,
                                                   float* __restrict__ ctx_out,
                                                   float* __restrict__ attn_out) {
  __shared__ float ebs[4][DD];        // 4 KB
  __shared__ float vsh[DD];           // 1 KB
  __shared__ float sc[4][LKK];        // 8 KB
  __shared__ float scratch[16 * 516]; // 33 KB (two-pass dq-reduce; later ctx-reduce)
  __shared__ float redm[4][4], reds[4][4];

  const int tid = threadIdx.x;
  const int b  = blockIdx.x >> 6;
  const int q0 = (blockIdx.x & 63) << 2;

  // stage Eb rows (4x256) and v
  if (tid < 256) {
    const int qi = tid >> 6, d4 = (tid & 63) << 2;
    *(float4*)&ebs[qi][d4] = *(const float4*)&Eb[(b * LQQ + q0 + qi) * DD + d4];
  } else if (tid < 320) {
    const int d4 = (tid - 256) << 2;
    *(float4*)&vsh[d4] = *(const float4*)&vvec[d4];
  }
  __syncthreads();

  // Sv = sum_d v[d] (uniform broadcast reads)
  float Sv = 0.f;
#pragma unroll
  for (int d4 = 0; d4 < DD; d4 += 4) {
    const float4 vv = *(const float4*)&vsh[d4];
    Sv += (vv.x + vv.y) + (vv.z + vv.w);
  }

  // ---- scores: acc[qi][ki] over this thread's 32-d eighth ----
  const int dq = tid >> 7;          // 0..7
  const int k4 = (tid & 127) << 2;  // 0..508
  const int db = dq << 5;           // d base (32 each)
  float acc[4][4] = {};
  const float* __restrict__ ea = &EaT[b * (DD * LKK) + db * LKK + k4];
#pragma unroll 2
  for (int i = 0; i < 32; i += 4) {
    const float4 vv  = *(const float4*)&vsh[db + i];
    const float4 e0q = *(const float4*)&ebs[0][db + i];
    const float4 e1q = *(const float4*)&ebs[1][db + i];
    const float4 e2q = *(const float4*)&ebs[2][db + i];
    const float4 e3q = *(const float4*)&ebs[3][db + i];
#pragma unroll
    for (int u = 0; u < 4; ++u) {
      const float4 a = *(const float4*)ea; ea += LKK;
      const float vd = COMP(vv, u);
      const float b0 = COMP(e0q, u), b1 = COMP(e1q, u), b2 = COMP(e2q, u), b3 = COMP(e3q, u);
      acc[0][0] = fmaf(vd, fast_rcp(fmaf(a.x, b0, 1.f)), acc[0][0]);
      acc[0][1] = fmaf(vd, fast_rcp(fmaf(a.y, b0, 1.f)), acc[0][1]);
      acc[0][2] = fmaf(vd, fast_rcp(fmaf(a.z, b0, 1.f)), acc[0][2]);
      acc[0][3] = fmaf(vd, fast_rcp(fmaf(a.w, b0, 1.f)), acc[0][3]);
      acc[1][0] = fmaf(vd, fast_rcp(fmaf(a.x, b1, 1.f)), acc[1][0]);
      acc[1][1] = fmaf(vd, fast_rcp(fmaf(a.y, b1, 1.f)), acc[1][1]);
      acc[1][2] = fmaf(vd, fast_rcp(fmaf(a.z, b1, 1.f)), acc[1][2]);
      acc[1][3] = fmaf(vd, fast_rcp(fmaf(a.w, b1, 1.f)), acc[1][3]);
      acc[2][0] = fmaf(vd, fast_rcp(fmaf(a.x, b2, 1.f)), acc[2][0]);
      acc[2][1] = fmaf(vd, fast_rcp(fmaf(a.y, b2, 1.f)), acc[2][1]);
      acc[2][2] = fmaf(vd, fast_rcp(fmaf(a.z, b2, 1.f)), acc[2][2]);
      acc[2][3] = fmaf(vd, fast_rcp(fmaf(a.w, b2, 1.f)), acc[2][3]);
      acc[3][0] = fmaf(vd, fast_rcp(fmaf(a.x, b3, 1.f)), acc[3][0]);
      acc[3][1] = fmaf(vd, fast_rcp(fmaf(a.y, b3, 1.f)), acc[3][1]);
      acc[3][2] = fmaf(vd, fast_rcp(fmaf(a.z, b3, 1.f)), acc[3][2]);
      acc[3][3] = fmaf(vd, fast_rcp(fmaf(a.w, b3, 1.f)), acc[3][3]);
    }
  }
  // two-pass partial reduce: dq 0..3 write, then dq 4..7 accumulate
  if (dq < 4) {
#pragma unroll
    for (int qi = 0; qi < 4; ++qi)
      *(float4*)&scratch[(dq * 4 + qi) * 516 + k4] =
          make_float4(acc[qi][0], acc[qi][1], acc[qi][2], acc[qi][3]);
  }
  __syncthreads();
  if (dq >= 4) {
#pragma unroll
    for (int qi = 0; qi < 4; ++qi) {
      float4 r = *(const float4*)&scratch[((dq - 4) * 4 + qi) * 516 + k4];
      r.x += acc[qi][0]; r.y += acc[qi][1]; r.z += acc[qi][2]; r.w += acc[qi][3];
      *(float4*)&scratch[((dq - 4) * 4 + qi) * 516 + k4] = r;
    }
  }
  __syncthreads();

  // ---- combine partials -> masked scaled scores in sc (512 threads) ----
  if (tid < 512) {
    const int qi = tid >> 7, j = (tid & 127) << 2;
    float4 s = make_float4(0.f, 0.f, 0.f, 0.f);
#pragma unroll
    for (int d = 0; d < 4; ++d) {
      const float4 r = *(const float4*)&scratch[(d * 4 + qi) * 516 + j];
      s.x += r.x; s.y += r.y; s.z += r.z; s.w += r.w;
    }
    const float inv_scale = 0.0625f;  // 1/sqrt(256)
    s.x = (Sv - 2.f * s.x) * inv_scale;
    s.y = (Sv - 2.f * s.y) * inv_scale;
    s.z = (Sv - 2.f * s.z) * inv_scale;
    s.w = (Sv - 2.f * s.w) * inv_scale;
    const int4 m4 = *(const int4*)&mask[(b * LQQ + q0 + qi) * LKK + j];
    if (m4.x == 0) s.x = -1e10f;
    if (m4.y == 0) s.y = -1e10f;
    if (m4.z == 0) s.z = -1e10f;
    if (m4.w == 0) s.w = -1e10f;
    *(float4*)&sc[qi][j] = s;
  }
  __syncthreads();

  // ---- softmax: 4 waves per q-row, 2 elems per thread ----
  {
    const int qi = tid >> 8, j = tid & 255;
    const int w4 = (tid >> 6) & 3;
    float x0 = sc[qi][j], x1 = sc[qi][j + 256];
    float mx = fmaxf(x0, x1);
#pragma unroll
    for (int off = 32; off; off >>= 1) mx = fmaxf(mx, __shfl_xor(mx, off));
    if ((tid & 63) == 0) redm[qi][w4] = mx;
    __syncthreads();
    mx = fmaxf(fmaxf(redm[qi][0], redm[qi][1]), fmaxf(redm[qi][2], redm[qi][3]));
    float p0 = fast_exp2((x0 - mx) * LOG2E);
    float p1 = fast_exp2((x1 - mx) * LOG2E);
    float sum = p0 + p1;
#pragma unroll
    for (int off = 32; off; off >>= 1) sum += __shfl_xor(sum, off);
    if ((tid & 63) == 0) reds[qi][w4] = sum;
    __syncthreads();
    sum = (reds[qi][0] + reds[qi][1]) + (reds[qi][2] + reds[qi][3]);
    const float inv = fast_rcp(sum);
    p0 *= inv; p1 *= inv;
    const int arow = (b * LQQ + q0 + qi) * LKK;
    attn_out[arow + j]       = p0;
    attn_out[arow + j + 256] = p1;
    sc[qi][j]       = p0;
    sc[qi][j + 256] = p1;
  }
  __syncthreads();

  // ---- context: thread = (k-16th, float4 d, all 4 q); two-pass reduce ----
  {
    const int kh = tid >> 6, d4i = (tid & 63) << 2;
    const int kbase = kh << 5;
    float4 c[4] = {};
    const float* __restrict__ vb = &value[(b * LKK + kbase) * DD + d4i];
    for (int kk = 0; kk < 32; kk += 4) {
      const float4 p0 = *(const float4*)&sc[0][kbase + kk];
      const float4 p1 = *(const float4*)&sc[1][kbase + kk];
      const float4 p2 = *(const float4*)&sc[2][kbase + kk];
      const float4 p3 = *(const float4*)&sc[3][kbase + kk];
#pragma unroll
      for (int u = 0; u < 4; ++u) {
        const float4 vv = *(const float4*)vb; vb += DD;
        const float a0 = COMP(p0, u), a1 = COMP(p1, u), a2 = COMP(p2, u), a3 = COMP(p3, u);
        c[0].x = fmaf(a0, vv.x, c[0].x); c[0].y = fmaf(a0, vv.y, c[0].y);
        c[0].z = fmaf(a0, vv.z, c[0].z); c[0].w = fmaf(a0, vv.w, c[0].w);
        c[1].x = fmaf(a1, vv.x, c[1].x); c[1].y = fmaf(a1, vv.y, c[1].y);
        c[1].z = fmaf(a1, vv.z, c[1].z); c[1].w = fmaf(a1, vv.w, c[1].w);
        c[2].x = fmaf(a2, vv.x, c[2].x); c[2].y = fmaf(a2, vv.y, c[2].y);
        c[2].z = fmaf(a2, vv.z, c[2].z); c[2].w = fmaf(a2, vv.w, c[2].w);
        c[3].x = fmaf(a3, vv.x, c[3].x); c[3].y = fmaf(a3, vv.y, c[3].y);
        c[3].z = fmaf(a3, vv.z, c[3].z); c[3].w = fmaf(a3, vv.w, c[3].w);
      }
    }
    if (kh < 8) {
#pragma unroll
      for (int qi = 0; qi < 4; ++qi)
        *(float4*)&scratch[(kh * 4 + qi) * DD + d4i] = c[qi];
    }
    __syncthreads();
    if (kh >= 8) {
#pragma unroll
      for (int qi = 0; qi < 4; ++qi) {
        float4 r = *(const float4*)&scratch[((kh - 8) * 4 + qi) * DD + d4i];
        r.x += c[qi].x; r.y += c[qi].y; r.z += c[qi].z; r.w += c[qi].w;
        *(float4*)&scratch[((kh - 8) * 4 + qi) * DD + d4i] = r;
      }
    }
  }
  __syncthreads();

  if (tid < 256) {
    const int qi = tid >> 6, d4 = (tid & 63) << 2;
    float4 s = make_float4(0.f, 0.f, 0.f, 0.f);
#pragma unroll
    for (int kh2 = 0; kh2 < 8; ++kh2) {
      const float4 r = *(const float4*)&scratch[(kh2 * 4 + qi) * DD + d4];
      s.x += r.x; s.y += r.y; s.z += r.z; s.w += r.w;
    }
    *(float4*)&ctx_out[(b * LQQ + q0 + qi) * DD + d4] = s;
  }
}

extern "C" void kernel_launch(void* const* d_in, const int* in_sizes, int n_in,
                              void* d_out, int out_size, void* d_ws, size_t ws_size,
                              hipStream_t stream) {
  const float* query = (const float*)d_in[0];
  const float* key   = (const float*)d_in[1];
  const float* value = (const float*)d_in[2];
  const float* W1    = (const float*)d_in[3];
  const float* W2    = (const float*)d_in[4];
  const float* v     = (const float*)d_in[5];
  const int*   mask  = (const int*)d_in[6];

  float* out      = (float*)d_out;
  float* ctx_out  = out;                       // [B, LQ, D]
  float* attn_out = out + BB * LQQ * DD;       // [B, LQ, LK]

  float* EaT = (float*)d_ws;                   // [B][D][LK] = 2 MB
  float* Eb  = EaT + BB * DD * LKK;            // [B*LQ][D]  = 1 MB

  dim3 g1(BB * LKK / 32 + BB * LQQ / 32, DD / 64);   // (96, 4)
  gemm_expk2<<<g1, 256, 0, stream>>>(key, query, W1, W2, EaT, Eb);

  attn_fused<<<BB * LQQ / 4, 1024, 0, stream>>>(EaT, Eb, v, value, mask, ctx_out, attn_out);
}

// Round 5
// 95.329 us; speedup vs baseline: 1.0495x; 1.0495x over previous
//
#include <hip/hip_runtime.h>
#include <math.h>

#define DD  256
#define LKK 512
#define LQQ 256
#define BB  4

constexpr float TWO_LOG2E = 2.8853900817779268f;  // 2*log2(e)
constexpr float LOG2E     = 1.4426950408889634f;

__device__ __forceinline__ float fast_rcp(float x)  { return __builtin_amdgcn_rcpf(x); }
__device__ __forceinline__ float fast_exp2(float x) { return __builtin_amdgcn_exp2f(x); }

#define COMP(v,u) ((u)==0?(v).x:(u)==1?(v).y:(u)==2?(v).z:(v).w)

// EaT[b][e][k] = exp(2 * key[b,k,:] . W1[e,:])  (d-major / transposed)
// Eb [b*LQ+q][e] = exp(2 * query[b,q,:] . W2[e,:])  (row-major)
// Software-pipelined: next k-tile loads issue before the current consume loop.
__global__ __launch_bounds__(256) void gemm_expk2(const float* __restrict__ key,
                                                  const float* __restrict__ query,
                                                  const float* __restrict__ W1,
                                                  const float* __restrict__ W2,
                                                  float* __restrict__ EaT,
                                                  float* __restrict__ Eb) {
  __shared__ float Xs[16][36];
  __shared__ float Ws[16][68];
  const int tid = threadIdx.x;
  const bool isK = blockIdx.x < (BB * LKK / 32);
  const float* __restrict__ X = isK ? key : query;
  const float* __restrict__ W = isK ? W1 : W2;
  const int m0 = (isK ? blockIdx.x : blockIdx.x - BB * LKK / 32) * 32;
  const int e0 = blockIdx.y * 64;

  const int r0 = (tid >> 4) << 1;   // 0..30
  const int c0 = (tid & 15) << 2;   // 0..60
  const int xr = tid >> 3, xc = (tid & 7) << 1;
  const int wr = tid >> 2, wc = (tid & 3) << 2;

  float2 xv = *(const float2*)&X[(m0 + xr) * DD + xc];
  float4 wv = *(const float4*)&W[(e0 + wr) * DD + wc];

  float acc[2][4] = {};
  for (int k0 = 0; k0 < DD; k0 += 16) {
    __syncthreads();
    Xs[xc][xr] = xv.x; Xs[xc + 1][xr] = xv.y;
    Ws[wc][wr] = wv.x; Ws[wc + 1][wr] = wv.y; Ws[wc + 2][wr] = wv.z; Ws[wc + 3][wr] = wv.w;
    __syncthreads();
    if (k0 + 16 < DD) {  // prefetch next tile; latency hides under the 128 FMAs below
      xv = *(const float2*)&X[(m0 + xr) * DD + k0 + 16 + xc];
      wv = *(const float4*)&W[(e0 + wr) * DD + k0 + 16 + wc];
    }
#pragma unroll
    for (int k = 0; k < 16; ++k) {
      const float2 a  = *(const float2*)&Xs[k][r0];
      const float4 bq = *(const float4*)&Ws[k][c0];
      acc[0][0] = fmaf(a.x, bq.x, acc[0][0]); acc[0][1] = fmaf(a.x, bq.y, acc[0][1]);
      acc[0][2] = fmaf(a.x, bq.z, acc[0][2]); acc[0][3] = fmaf(a.x, bq.w, acc[0][3]);
      acc[1][0] = fmaf(a.y, bq.x, acc[1][0]); acc[1][1] = fmaf(a.y, bq.y, acc[1][1]);
      acc[1][2] = fmaf(a.y, bq.z, acc[1][2]); acc[1][3] = fmaf(a.y, bq.w, acc[1][3]);
    }
  }
  if (isK) {
    const int b = m0 >> 9;
    const int kloc = (m0 & 511) + r0;
#pragma unroll
    for (int j = 0; j < 4; ++j) {
      float2 o;
      o.x = fast_exp2(acc[0][j] * TWO_LOG2E);
      o.y = fast_exp2(acc[1][j] * TWO_LOG2E);
      *(float2*)&EaT[b * (DD * LKK) + (e0 + c0 + j) * LKK + kloc] = o;
    }
  } else {
#pragma unroll
    for (int i = 0; i < 2; ++i) {
      float4 o;
      o.x = fast_exp2(acc[i][0] * TWO_LOG2E);
      o.y = fast_exp2(acc[i][1] * TWO_LOG2E);
      o.z = fast_exp2(acc[i][2] * TWO_LOG2E);
      o.w = fast_exp2(acc[i][3] * TWO_LOG2E);
      *(float4*)&Eb[(m0 + r0 + i) * DD + e0 + c0] = o;
    }
  }
}

// One block per (b, 2 q-rows): 512 blocks x 512 threads => 2 blocks/CU,
// 4 waves/SIMD at VGPR<=128 (pinned by launch_bounds).
__global__ __launch_bounds__(512, 4) void attn_fused(const float* __restrict__ EaT,
                                                     const float* __restrict__ Eb,
                                                     const float* __restrict__ vvec,
                                                     const float* __restrict__ value,
                                                     const int* __restrict__ mask,
                                                     float* __restrict__ ctx_out,
                                                     float* __restrict__ attn_out) {
  __shared__ float ebs[2][DD];        // 2 KB
  __shared__ float vsh[DD];           // 1 KB
  __shared__ float sc[2][LKK];        // 4 KB
  __shared__ float scratch[8 * 516];  // 16.5 KB (dq-reduce; later ctx-reduce)
  __shared__ float redm[2][4], reds[2][4];

  const int tid = threadIdx.x;
  const int b  = blockIdx.x >> 7;
  const int q0 = (blockIdx.x & 127) << 1;

  // stage Eb rows (2x256) and v
  if (tid < 128) {
    const int qi = tid >> 6, d4 = (tid & 63) << 2;
    *(float4*)&ebs[qi][d4] = *(const float4*)&Eb[(b * LQQ + q0 + qi) * DD + d4];
  } else if (tid < 192) {
    const int d4 = (tid - 128) << 2;
    *(float4*)&vsh[d4] = *(const float4*)&vvec[d4];
  }
  __syncthreads();

  // Sv = sum_d v[d] (uniform broadcast reads)
  float Sv = 0.f;
#pragma unroll
  for (int d4 = 0; d4 < DD; d4 += 4) {
    const float4 vv = *(const float4*)&vsh[d4];
    Sv += (vv.x + vv.y) + (vv.z + vv.w);
  }

  // ---- scores: acc[qi][ki] over this thread's 64-d quarter, 2 q-rows ----
  const int dq = tid >> 7;          // 0..3
  const int k4 = (tid & 127) << 2;  // 0..508
  const int db = dq << 6;           // d base (64 each)
  float acc[2][4] = {};
  const float* __restrict__ ea = &EaT[b * (DD * LKK) + db * LKK + k4];
#pragma unroll 2
  for (int i = 0; i < 64; i += 4) {
    const float4 vv  = *(const float4*)&vsh[db + i];
    const float4 e0q = *(const float4*)&ebs[0][db + i];
    const float4 e1q = *(const float4*)&ebs[1][db + i];
#pragma unroll
    for (int u = 0; u < 4; ++u) {
      const float4 a = *(const float4*)ea; ea += LKK;
      const float vd = COMP(vv, u);
      const float b0 = COMP(e0q, u), b1 = COMP(e1q, u);
      acc[0][0] = fmaf(vd, fast_rcp(fmaf(a.x, b0, 1.f)), acc[0][0]);
      acc[0][1] = fmaf(vd, fast_rcp(fmaf(a.y, b0, 1.f)), acc[0][1]);
      acc[0][2] = fmaf(vd, fast_rcp(fmaf(a.z, b0, 1.f)), acc[0][2]);
      acc[0][3] = fmaf(vd, fast_rcp(fmaf(a.w, b0, 1.f)), acc[0][3]);
      acc[1][0] = fmaf(vd, fast_rcp(fmaf(a.x, b1, 1.f)), acc[1][0]);
      acc[1][1] = fmaf(vd, fast_rcp(fmaf(a.y, b1, 1.f)), acc[1][1]);
      acc[1][2] = fmaf(vd, fast_rcp(fmaf(a.z, b1, 1.f)), acc[1][2]);
      acc[1][3] = fmaf(vd, fast_rcp(fmaf(a.w, b1, 1.f)), acc[1][3]);
    }
  }
  // write dq-partials (conflict-free b128)
#pragma unroll
  for (int qi = 0; qi < 2; ++qi)
    *(float4*)&scratch[(dq * 2 + qi) * 516 + k4] =
        make_float4(acc[qi][0], acc[qi][1], acc[qi][2], acc[qi][3]);
  __syncthreads();

  // ---- combine partials -> masked scaled scores in sc (512 thr, float2 each) ----
  {
    const int qi = tid >> 8, j2 = (tid & 255) << 1;
    float2 s = make_float2(0.f, 0.f);
#pragma unroll
    for (int d = 0; d < 4; ++d) {
      const float2 r = *(const float2*)&scratch[(d * 2 + qi) * 516 + j2];
      s.x += r.x; s.y += r.y;
    }
    const float inv_scale = 0.0625f;  // 1/sqrt(256)
    s.x = (Sv - 2.f * s.x) * inv_scale;
    s.y = (Sv - 2.f * s.y) * inv_scale;
    const int2 m2 = *(const int2*)&mask[(b * LQQ + q0 + qi) * LKK + j2];
    if (m2.x == 0) s.x = -1e10f;
    if (m2.y == 0) s.y = -1e10f;
    *(float2*)&sc[qi][j2] = s;
  }
  __syncthreads();

  // ---- softmax: 4 waves per q-row, 2 elems per thread ----
  {
    const int qi = tid >> 8, j = tid & 255;
    const int w4 = (tid >> 6) & 3;
    float x0 = sc[qi][j], x1 = sc[qi][j + 256];
    float mx = fmaxf(x0, x1);
#pragma unroll
    for (int off = 32; off; off >>= 1) mx = fmaxf(mx, __shfl_xor(mx, off));
    if ((tid & 63) == 0) redm[qi][w4] = mx;
    __syncthreads();
    mx = fmaxf(fmaxf(redm[qi][0], redm[qi][1]), fmaxf(redm[qi][2], redm[qi][3]));
    float p0 = fast_exp2((x0 - mx) * LOG2E);
    float p1 = fast_exp2((x1 - mx) * LOG2E);
    float sum = p0 + p1;
#pragma unroll
    for (int off = 32; off; off >>= 1) sum += __shfl_xor(sum, off);
    if ((tid & 63) == 0) reds[qi][w4] = sum;
    __syncthreads();
    sum = (reds[qi][0] + reds[qi][1]) + (reds[qi][2] + reds[qi][3]);
    const float inv = fast_rcp(sum);
    p0 *= inv; p1 *= inv;
    const int arow = (b * LQQ + q0 + qi) * LKK;
    attn_out[arow + j]       = p0;
    attn_out[arow + j + 256] = p1;
    sc[qi][j]       = p0;
    sc[qi][j + 256] = p1;
  }
  __syncthreads();

  // ---- context: thread = (k-eighth, float4 d, both q); LDS reduce ----
  {
    const int kh = tid >> 6, d4i = (tid & 63) << 2;
    const int kbase = kh << 6;
    float4 c[2] = {};
    const float* __restrict__ vb = &value[(b * LKK + kbase) * DD + d4i];
    for (int kk = 0; kk < 64; kk += 4) {
      const float4 p0 = *(const float4*)&sc[0][kbase + kk];
      const float4 p1 = *(const float4*)&sc[1][kbase + kk];
#pragma unroll
      for (int u = 0; u < 4; ++u) {
        const float4 vv = *(const float4*)vb; vb += DD;
        const float a0 = COMP(p0, u), a1 = COMP(p1, u);
        c[0].x = fmaf(a0, vv.x, c[0].x); c[0].y = fmaf(a0, vv.y, c[0].y);
        c[0].z = fmaf(a0, vv.z, c[0].z); c[0].w = fmaf(a0, vv.w, c[0].w);
        c[1].x = fmaf(a1, vv.x, c[1].x); c[1].y = fmaf(a1, vv.y, c[1].y);
        c[1].z = fmaf(a1, vv.z, c[1].z); c[1].w = fmaf(a1, vv.w, c[1].w);
      }
    }
    __syncthreads();  // sc reads done before scratch reuse
#pragma unroll
    for (int qi = 0; qi < 2; ++qi)
      *(float4*)&scratch[(kh * 2 + qi) * DD + d4i] = c[qi];
  }
  __syncthreads();

  if (tid < 128) {
    const int qi = tid >> 6, d4 = (tid & 63) << 2;
    float4 s = make_float4(0.f, 0.f, 0.f, 0.f);
#pragma unroll
    for (int kh2 = 0; kh2 < 8; ++kh2) {
      const float4 r = *(const float4*)&scratch[(kh2 * 2 + qi) * DD + d4];
      s.x += r.x; s.y += r.y; s.z += r.z; s.w += r.w;
    }
    *(float4*)&ctx_out[(b * LQQ + q0 + qi) * DD + d4] = s;
  }
}

extern "C" void kernel_launch(void* const* d_in, const int* in_sizes, int n_in,
                              void* d_out, int out_size, void* d_ws, size_t ws_size,
                              hipStream_t stream) {
  const float* query = (const float*)d_in[0];
  const float* key   = (const float*)d_in[1];
  const float* value = (const float*)d_in[2];
  const float* W1    = (const float*)d_in[3];
  const float* W2    = (const float*)d_in[4];
  const float* v     = (const float*)d_in[5];
  const int*   mask  = (const int*)d_in[6];

  float* out      = (float*)d_out;
  float* ctx_out  = out;                       // [B, LQ, D]
  float* attn_out = out + BB * LQQ * DD;       // [B, LQ, LK]

  float* EaT = (float*)d_ws;                   // [B][D][LK] = 2 MB
  float* Eb  = EaT + BB * DD * LKK;            // [B*LQ][D]  = 1 MB

  dim3 g1(BB * LKK / 32 + BB * LQQ / 32, DD / 64);   // (96, 4)
  gemm_expk2<<<g1, 256, 0, stream>>>(key, query, W1, W2, EaT, Eb);

  attn_fused<<<BB * LQQ / 2, 512, 0, stream>>>(EaT, Eb, v, value, mask, ctx_out, attn_out);
}

// Round 6
// 94.447 us; speedup vs baseline: 1.0593x; 1.0093x over previous
//
#include <hip/hip_runtime.h>
#include <math.h>

#define DD  256
#define LKK 512
#define LQQ 256
#define BB  4

constexpr float TWO_LOG2E = 2.8853900817779268f;  // 2*log2(e)
constexpr float LOG2E     = 1.4426950408889634f;

__device__ __forceinline__ float fast_rcp(float x)  { return __builtin_amdgcn_rcpf(x); }
__device__ __forceinline__ float fast_exp2(float x) { return __builtin_amdgcn_exp2f(x); }

#define COMP(v,u) ((u)==0?(v).x:(u)==1?(v).y:(u)==2?(v).z:(v).w)

// EaT[b][e][k] = exp(2 * key[b,k,:] . W1[e,:])  (d-major / transposed)
// Eb [b*LQ+q][e] = exp(2 * query[b,q,:] . W2[e,:])  (row-major)
// Software-pipelined: next k-tile loads issue before the current consume loop.
__global__ __launch_bounds__(256) void gemm_expk2(const float* __restrict__ key,
                                                  const float* __restrict__ query,
                                                  const float* __restrict__ W1,
                                                  const float* __restrict__ W2,
                                                  float* __restrict__ EaT,
                                                  float* __restrict__ Eb) {
  __shared__ float Xs[16][36];
  __shared__ float Ws[16][68];
  const int tid = threadIdx.x;
  const bool isK = blockIdx.x < (BB * LKK / 32);
  const float* __restrict__ X = isK ? key : query;
  const float* __restrict__ W = isK ? W1 : W2;
  const int m0 = (isK ? blockIdx.x : blockIdx.x - BB * LKK / 32) * 32;
  const int e0 = blockIdx.y * 64;

  const int r0 = (tid >> 4) << 1;   // 0..30
  const int c0 = (tid & 15) << 2;   // 0..60
  const int xr = tid >> 3, xc = (tid & 7) << 1;
  const int wr = tid >> 2, wc = (tid & 3) << 2;

  float2 xv = *(const float2*)&X[(m0 + xr) * DD + xc];
  float4 wv = *(const float4*)&W[(e0 + wr) * DD + wc];

  float acc[2][4] = {};
  for (int k0 = 0; k0 < DD; k0 += 16) {
    __syncthreads();
    Xs[xc][xr] = xv.x; Xs[xc + 1][xr] = xv.y;
    Ws[wc][wr] = wv.x; Ws[wc + 1][wr] = wv.y; Ws[wc + 2][wr] = wv.z; Ws[wc + 3][wr] = wv.w;
    __syncthreads();
    if (k0 + 16 < DD) {  // prefetch next tile; latency hides under the 128 FMAs below
      xv = *(const float2*)&X[(m0 + xr) * DD + k0 + 16 + xc];
      wv = *(const float4*)&W[(e0 + wr) * DD + k0 + 16 + wc];
    }
#pragma unroll
    for (int k = 0; k < 16; ++k) {
      const float2 a  = *(const float2*)&Xs[k][r0];
      const float4 bq = *(const float4*)&Ws[k][c0];
      acc[0][0] = fmaf(a.x, bq.x, acc[0][0]); acc[0][1] = fmaf(a.x, bq.y, acc[0][1]);
      acc[0][2] = fmaf(a.x, bq.z, acc[0][2]); acc[0][3] = fmaf(a.x, bq.w, acc[0][3]);
      acc[1][0] = fmaf(a.y, bq.x, acc[1][0]); acc[1][1] = fmaf(a.y, bq.y, acc[1][1]);
      acc[1][2] = fmaf(a.y, bq.z, acc[1][2]); acc[1][3] = fmaf(a.y, bq.w, acc[1][3]);
    }
  }
  if (isK) {
    const int b = m0 >> 9;
    const int kloc = (m0 & 511) + r0;
#pragma unroll
    for (int j = 0; j < 4; ++j) {
      float2 o;
      o.x = fast_exp2(acc[0][j] * TWO_LOG2E);
      o.y = fast_exp2(acc[1][j] * TWO_LOG2E);
      *(float2*)&EaT[b * (DD * LKK) + (e0 + c0 + j) * LKK + kloc] = o;
    }
  } else {
#pragma unroll
    for (int i = 0; i < 2; ++i) {
      float4 o;
      o.x = fast_exp2(acc[i][0] * TWO_LOG2E);
      o.y = fast_exp2(acc[i][1] * TWO_LOG2E);
      o.z = fast_exp2(acc[i][2] * TWO_LOG2E);
      o.w = fast_exp2(acc[i][3] * TWO_LOG2E);
      *(float4*)&Eb[(m0 + r0 + i) * DD + e0 + c0] = o;
    }
  }
}

// One block per (b, 2 q-rows): 512 blocks x 512 threads => 2 blocks/CU,
// 16 waves/CU at VGPR~128 (no min-waves pin: R5 showed launch_bounds(512,4)
// makes the allocator drop to 64 VGPR and spill 200MB; plain (512) gives 128/no-spill).
__global__ __launch_bounds__(512) void attn_fused(const float* __restrict__ EaT,
                                                  const float* __restrict__ Eb,
                                                  const float* __restrict__ vvec,
                                                  const float* __restrict__ value,
                                                  const int* __restrict__ mask,
                                                  float* __restrict__ ctx_out,
                                                  float* __restrict__ attn_out) {
  __shared__ float ebs[2][DD];        // 2 KB
  __shared__ float vsh[DD];           // 1 KB
  __shared__ float sc[2][LKK];        // 4 KB
  __shared__ float scratch[8 * 516];  // 16.5 KB (dq-reduce; later ctx-reduce)
  __shared__ float redm[2][4], reds[2][4];

  const int tid = threadIdx.x;
  const int b  = blockIdx.x >> 7;
  const int q0 = (blockIdx.x & 127) << 1;

  // stage Eb rows (2x256) and v
  if (tid < 128) {
    const int qi = tid >> 6, d4 = (tid & 63) << 2;
    *(float4*)&ebs[qi][d4] = *(const float4*)&Eb[(b * LQQ + q0 + qi) * DD + d4];
  } else if (tid < 192) {
    const int d4 = (tid - 128) << 2;
    *(float4*)&vsh[d4] = *(const float4*)&vvec[d4];
  }
  __syncthreads();

  // Sv = sum_d v[d] (uniform broadcast reads)
  float Sv = 0.f;
#pragma unroll
  for (int d4 = 0; d4 < DD; d4 += 4) {
    const float4 vv = *(const float4*)&vsh[d4];
    Sv += (vv.x + vv.y) + (vv.z + vv.w);
  }

  // ---- scores: acc[qi][ki] over this thread's 64-d quarter, 2 q-rows ----
  const int dq = tid >> 7;          // 0..3
  const int k4 = (tid & 127) << 2;  // 0..508
  const int db = dq << 6;           // d base (64 each)
  float acc[2][4] = {};
  const float* __restrict__ ea = &EaT[b * (DD * LKK) + db * LKK + k4];
#pragma unroll 2
  for (int i = 0; i < 64; i += 4) {
    const float4 vv  = *(const float4*)&vsh[db + i];
    const float4 e0q = *(const float4*)&ebs[0][db + i];
    const float4 e1q = *(const float4*)&ebs[1][db + i];
#pragma unroll
    for (int u = 0; u < 4; ++u) {
      const float4 a = *(const float4*)ea; ea += LKK;
      const float vd = COMP(vv, u);
      const float b0 = COMP(e0q, u), b1 = COMP(e1q, u);
      acc[0][0] = fmaf(vd, fast_rcp(fmaf(a.x, b0, 1.f)), acc[0][0]);
      acc[0][1] = fmaf(vd, fast_rcp(fmaf(a.y, b0, 1.f)), acc[0][1]);
      acc[0][2] = fmaf(vd, fast_rcp(fmaf(a.z, b0, 1.f)), acc[0][2]);
      acc[0][3] = fmaf(vd, fast_rcp(fmaf(a.w, b0, 1.f)), acc[0][3]);
      acc[1][0] = fmaf(vd, fast_rcp(fmaf(a.x, b1, 1.f)), acc[1][0]);
      acc[1][1] = fmaf(vd, fast_rcp(fmaf(a.y, b1, 1.f)), acc[1][1]);
      acc[1][2] = fmaf(vd, fast_rcp(fmaf(a.z, b1, 1.f)), acc[1][2]);
      acc[1][3] = fmaf(vd, fast_rcp(fmaf(a.w, b1, 1.f)), acc[1][3]);
    }
  }
  // write dq-partials (conflict-free b128)
#pragma unroll
  for (int qi = 0; qi < 2; ++qi)
    *(float4*)&scratch[(dq * 2 + qi) * 516 + k4] =
        make_float4(acc[qi][0], acc[qi][1], acc[qi][2], acc[qi][3]);
  __syncthreads();

  // ---- combine partials -> masked scaled scores in sc (512 thr, float2 each) ----
  {
    const int qi = tid >> 8, j2 = (tid & 255) << 1;
    float2 s = make_float2(0.f, 0.f);
#pragma unroll
    for (int d = 0; d < 4; ++d) {
      const float2 r = *(const float2*)&scratch[(d * 2 + qi) * 516 + j2];
      s.x += r.x; s.y += r.y;
    }
    const float inv_scale = 0.0625f;  // 1/sqrt(256)
    s.x = (Sv - 2.f * s.x) * inv_scale;
    s.y = (Sv - 2.f * s.y) * inv_scale;
    const int2 m2 = *(const int2*)&mask[(b * LQQ + q0 + qi) * LKK + j2];
    if (m2.x == 0) s.x = -1e10f;
    if (m2.y == 0) s.y = -1e10f;
    *(float2*)&sc[qi][j2] = s;
  }
  __syncthreads();

  // ---- softmax: 4 waves per q-row, 2 elems per thread ----
  {
    const int qi = tid >> 8, j = tid & 255;
    const int w4 = (tid >> 6) & 3;
    float x0 = sc[qi][j], x1 = sc[qi][j + 256];
    float mx = fmaxf(x0, x1);
#pragma unroll
    for (int off = 32; off; off >>= 1) mx = fmaxf(mx, __shfl_xor(mx, off));
    if ((tid & 63) == 0) redm[qi][w4] = mx;
    __syncthreads();
    mx = fmaxf(fmaxf(redm[qi][0], redm[qi][1]), fmaxf(redm[qi][2], redm[qi][3]));
    float p0 = fast_exp2((x0 - mx) * LOG2E);
    float p1 = fast_exp2((x1 - mx) * LOG2E);
    float sum = p0 + p1;
#pragma unroll
    for (int off = 32; off; off >>= 1) sum += __shfl_xor(sum, off);
    if ((tid & 63) == 0) reds[qi][w4] = sum;
    __syncthreads();
    sum = (reds[qi][0] + reds[qi][1]) + (reds[qi][2] + reds[qi][3]);
    const float inv = fast_rcp(sum);
    p0 *= inv; p1 *= inv;
    const int arow = (b * LQQ + q0 + qi) * LKK;
    attn_out[arow + j]       = p0;
    attn_out[arow + j + 256] = p1;
    sc[qi][j]       = p0;
    sc[qi][j + 256] = p1;
  }
  __syncthreads();

  // ---- context: thread = (k-eighth, float4 d, both q); LDS reduce ----
  {
    const int kh = tid >> 6, d4i = (tid & 63) << 2;
    const int kbase = kh << 6;
    float4 c[2] = {};
    const float* __restrict__ vb = &value[(b * LKK + kbase) * DD + d4i];
    for (int kk = 0; kk < 64; kk += 4) {
      const float4 p0 = *(const float4*)&sc[0][kbase + kk];
      const float4 p1 = *(const float4*)&sc[1][kbase + kk];
#pragma unroll
      for (int u = 0; u < 4; ++u) {
        const float4 vv = *(const float4*)vb; vb += DD;
        const float a0 = COMP(p0, u), a1 = COMP(p1, u);
        c[0].x = fmaf(a0, vv.x, c[0].x); c[0].y = fmaf(a0, vv.y, c[0].y);
        c[0].z = fmaf(a0, vv.z, c[0].z); c[0].w = fmaf(a0, vv.w, c[0].w);
        c[1].x = fmaf(a1, vv.x, c[1].x); c[1].y = fmaf(a1, vv.y, c[1].y);
        c[1].z = fmaf(a1, vv.z, c[1].z); c[1].w = fmaf(a1, vv.w, c[1].w);
      }
    }
    __syncthreads();  // sc reads done before scratch reuse
#pragma unroll
    for (int qi = 0; qi < 2; ++qi)
      *(float4*)&scratch[(kh * 2 + qi) * DD + d4i] = c[qi];
  }
  __syncthreads();

  if (tid < 128) {
    const int qi = tid >> 6, d4 = (tid & 63) << 2;
    float4 s = make_float4(0.f, 0.f, 0.f, 0.f);
#pragma unroll
    for (int kh2 = 0; kh2 < 8; ++kh2) {
      const float4 r = *(const float4*)&scratch[(kh2 * 2 + qi) * DD + d4];
      s.x += r.x; s.y += r.y; s.z += r.z; s.w += r.w;
    }
    *(float4*)&ctx_out[(b * LQQ + q0 + qi) * DD + d4] = s;
  }
}

extern "C" void kernel_launch(void* const* d_in, const int* in_sizes, int n_in,
                              void* d_out, int out_size, void* d_ws, size_t ws_size,
                              hipStream_t stream) {
  const float* query = (const float*)d_in[0];
  const float* key   = (const float*)d_in[1];
  const float* value = (const float*)d_in[2];
  const float* W1    = (const float*)d_in[3];
  const float* W2    = (const float*)d_in[4];
  const float* v     = (const float*)d_in[5];
  const int*   mask  = (const int*)d_in[6];

  float* out      = (float*)d_out;
  float* ctx_out  = out;                       // [B, LQ, D]
  float* attn_out = out + BB * LQQ * DD;       // [B, LQ, LK]

  float* EaT = (float*)d_ws;                   // [B][D][LK] = 2 MB
  float* Eb  = EaT + BB * DD * LKK;            // [B*LQ][D]  = 1 MB

  dim3 g1(BB * LKK / 32 + BB * LQQ / 32, DD / 64);   // (96, 4)
  gemm_expk2<<<g1, 256, 0, stream>>>(key, query, W1, W2, EaT, Eb);

  attn_fused<<<BB * LQQ / 2, 512, 0, stream>>>(EaT, Eb, v, value, mask, ctx_out, attn_out);
}

// Round 7
// 86.990 us; speedup vs baseline: 1.1501x; 1.0857x over previous
//
#include <hip/hip_runtime.h>
#include <math.h>

#define DD  256
#define LKK 512
#define LQQ 256
#define BB  4

constexpr float TWO_LOG2E = 2.8853900817779268f;  // 2*log2(e)
constexpr float LOG2E     = 1.4426950408889634f;

__device__ __forceinline__ float fast_rcp(float x)  { return __builtin_amdgcn_rcpf(x); }
__device__ __forceinline__ float fast_exp2(float x) { return __builtin_amdgcn_exp2f(x); }

#define COMP(v,u) ((u)==0?(v).x:(u)==1?(v).y:(u)==2?(v).z:(v).w)

// EaT[b][e][k] = exp(2 * key[b,k,:] . W1[e,:])  (d-major / transposed)
// Eb [b*LQ+q][e] = exp(2 * query[b,q,:] . W2[e,:])  (row-major)
// (unchanged from R3 — proven correct; next optimization target)
__global__ __launch_bounds__(256) void gemm_expk2(const float* __restrict__ key,
                                                  const float* __restrict__ query,
                                                  const float* __restrict__ W1,
                                                  const float* __restrict__ W2,
                                                  float* __restrict__ EaT,
                                                  float* __restrict__ Eb) {
  __shared__ float Xs[16][36];
  __shared__ float Ws[16][68];
  const int tid = threadIdx.x;
  const bool isK = blockIdx.x < (BB * LKK / 32);
  const float* __restrict__ X = isK ? key : query;
  const float* __restrict__ W = isK ? W1 : W2;
  const int m0 = (isK ? blockIdx.x : blockIdx.x - BB * LKK / 32) * 32;
  const int e0 = blockIdx.y * 64;

  const int r0 = (tid >> 4) << 1;   // 0..30
  const int c0 = (tid & 15) << 2;   // 0..60
  const int xr = tid >> 3, xc = (tid & 7) << 1;
  const int wr = tid >> 2, wc = (tid & 3) << 2;

  float2 xv = *(const float2*)&X[(m0 + xr) * DD + xc];
  float4 wv = *(const float4*)&W[(e0 + wr) * DD + wc];

  float acc[2][4] = {};
  for (int k0 = 0; k0 < DD; k0 += 16) {
    __syncthreads();
    Xs[xc][xr] = xv.x; Xs[xc + 1][xr] = xv.y;
    Ws[wc][wr] = wv.x; Ws[wc + 1][wr] = wv.y; Ws[wc + 2][wr] = wv.z; Ws[wc + 3][wr] = wv.w;
    __syncthreads();
    if (k0 + 16 < DD) {
      xv = *(const float2*)&X[(m0 + xr) * DD + k0 + 16 + xc];
      wv = *(const float4*)&W[(e0 + wr) * DD + k0 + 16 + wc];
    }
#pragma unroll
    for (int k = 0; k < 16; ++k) {
      const float2 a  = *(const float2*)&Xs[k][r0];
      const float4 bq = *(const float4*)&Ws[k][c0];
      acc[0][0] = fmaf(a.x, bq.x, acc[0][0]); acc[0][1] = fmaf(a.x, bq.y, acc[0][1]);
      acc[0][2] = fmaf(a.x, bq.z, acc[0][2]); acc[0][3] = fmaf(a.x, bq.w, acc[0][3]);
      acc[1][0] = fmaf(a.y, bq.x, acc[1][0]); acc[1][1] = fmaf(a.y, bq.y, acc[1][1]);
      acc[1][2] = fmaf(a.y, bq.z, acc[1][2]); acc[1][3] = fmaf(a.y, bq.w, acc[1][3]);
    }
  }
  if (isK) {
    const int b = m0 >> 9;
    const int kloc = (m0 & 511) + r0;
#pragma unroll
    for (int j = 0; j < 4; ++j) {
      float2 o;
      o.x = fast_exp2(acc[0][j] * TWO_LOG2E);
      o.y = fast_exp2(acc[1][j] * TWO_LOG2E);
      *(float2*)&EaT[b * (DD * LKK) + (e0 + c0 + j) * LKK + kloc] = o;
    }
  } else {
#pragma unroll
    for (int i = 0; i < 2; ++i) {
      float4 o;
      o.x = fast_exp2(acc[i][0] * TWO_LOG2E);
      o.y = fast_exp2(acc[i][1] * TWO_LOG2E);
      o.z = fast_exp2(acc[i][2] * TWO_LOG2E);
      o.w = fast_exp2(acc[i][3] * TWO_LOG2E);
      *(float4*)&Eb[(m0 + r0 + i) * DD + e0 + c0] = o;
    }
  }
}

// Kernel A: masked scaled scores -> Sws (the attn region of d_out).
// Grid 1024 blocks x 256 thr (4-wave blocks -> 4 blocks/CU, 16 waves/CU).
// Block = (b, 4 q-rows, 128-k tile). Thread = (32-d slice, k-quad).
__global__ __launch_bounds__(256) void scores_k(const float* __restrict__ EaT,
                                                const float* __restrict__ Eb,
                                                const float* __restrict__ vvec,
                                                const int* __restrict__ mask,
                                                float* __restrict__ Sws) {
  __shared__ float ebs[4][DD];       // 4 KB
  __shared__ float vsh[DD];          // 1 KB
  __shared__ float red[8][4][128];   // 16 KB
  const int tid = threadIdx.x;
  const int bid = blockIdx.x;
  const int b  = bid >> 8;
  const int r  = bid & 255;
  const int q0 = (r >> 2) << 2;      // 0..252 step 4
  const int k0 = (r & 3) << 7;       // 0,128,256,384

  {
    const int qi = tid >> 6, d4 = (tid & 63) << 2;
    *(float4*)&ebs[qi][d4] = *(const float4*)&Eb[(b * LQQ + q0 + qi) * DD + d4];
  }
  if (tid < 64) *(float4*)&vsh[tid << 2] = *(const float4*)&vvec[tid << 2];
  __syncthreads();

  float Sv = 0.f;
#pragma unroll
  for (int d4 = 0; d4 < DD; d4 += 4) {
    const float4 vv = *(const float4*)&vsh[d4];
    Sv += (vv.x + vv.y) + (vv.z + vv.w);
  }

  const int ds = tid >> 5;           // 0..7 (32-d slice)
  const int kq = (tid & 31) << 2;    // 0..124 (k-quad within tile)
  float acc[4][4] = {};
  const float* __restrict__ ea = &EaT[(b * DD + ds * 32) * LKK + k0 + kq];
#pragma unroll 4
  for (int i = 0; i < 32; ++i) {
    const float4 a = *(const float4*)&ea[i * LKK];
    const int d = ds * 32 + i;
    const float vd = vsh[d];
    const float b0 = ebs[0][d], b1 = ebs[1][d], b2 = ebs[2][d], b3 = ebs[3][d];
    acc[0][0] = fmaf(vd, fast_rcp(fmaf(a.x, b0, 1.f)), acc[0][0]);
    acc[0][1] = fmaf(vd, fast_rcp(fmaf(a.y, b0, 1.f)), acc[0][1]);
    acc[0][2] = fmaf(vd, fast_rcp(fmaf(a.z, b0, 1.f)), acc[0][2]);
    acc[0][3] = fmaf(vd, fast_rcp(fmaf(a.w, b0, 1.f)), acc[0][3]);
    acc[1][0] = fmaf(vd, fast_rcp(fmaf(a.x, b1, 1.f)), acc[1][0]);
    acc[1][1] = fmaf(vd, fast_rcp(fmaf(a.y, b1, 1.f)), acc[1][1]);
    acc[1][2] = fmaf(vd, fast_rcp(fmaf(a.z, b1, 1.f)), acc[1][2]);
    acc[1][3] = fmaf(vd, fast_rcp(fmaf(a.w, b1, 1.f)), acc[1][3]);
    acc[2][0] = fmaf(vd, fast_rcp(fmaf(a.x, b2, 1.f)), acc[2][0]);
    acc[2][1] = fmaf(vd, fast_rcp(fmaf(a.y, b2, 1.f)), acc[2][1]);
    acc[2][2] = fmaf(vd, fast_rcp(fmaf(a.z, b2, 1.f)), acc[2][2]);
    acc[2][3] = fmaf(vd, fast_rcp(fmaf(a.w, b2, 1.f)), acc[2][3]);
    acc[3][0] = fmaf(vd, fast_rcp(fmaf(a.x, b3, 1.f)), acc[3][0]);
    acc[3][1] = fmaf(vd, fast_rcp(fmaf(a.y, b3, 1.f)), acc[3][1]);
    acc[3][2] = fmaf(vd, fast_rcp(fmaf(a.z, b3, 1.f)), acc[3][2]);
    acc[3][3] = fmaf(vd, fast_rcp(fmaf(a.w, b3, 1.f)), acc[3][3]);
  }
#pragma unroll
  for (int q = 0; q < 4; ++q)
    *(float4*)&red[ds][q][kq] = make_float4(acc[q][0], acc[q][1], acc[q][2], acc[q][3]);
  __syncthreads();

  {
    const int o = tid << 1;          // 0..510 (2 outputs/thread)
    const int q = o >> 7, k = o & 127;
    float2 s = make_float2(0.f, 0.f);
#pragma unroll
    for (int d = 0; d < 8; ++d) {
      const float2 rr = *(const float2*)&red[d][q][k];
      s.x += rr.x; s.y += rr.y;
    }
    const float inv_scale = 0.0625f;  // 1/sqrt(256)
    s.x = (Sv - 2.f * s.x) * inv_scale;
    s.y = (Sv - 2.f * s.y) * inv_scale;
    const int row = (b * LQQ + q0 + q) * LKK + k0 + k;
    const int2 m2 = *(const int2*)&mask[row];
    if (m2.x == 0) s.x = -1e10f;
    if (m2.y == 0) s.y = -1e10f;
    *(float2*)&Sws[row] = s;
  }
}

// Kernel B: softmax + attention out + context. 512 blocks x 256 thr.
// Block = (b, 2 q-rows). attn_io holds raw scores on entry (written by scores_k),
// probabilities on exit. Reads complete before writes via __syncthreads.
__global__ __launch_bounds__(256) void smax_ctx(const float* __restrict__ value,
                                                float* attn_io,
                                                float* __restrict__ ctx_out) {
  __shared__ float sc[2][LKK];       // 4 KB
  __shared__ float scr[4][2][DD];    // 8 KB
  __shared__ float redm[2][2], reds[2][2];
  const int tid = threadIdx.x;
  const int b  = blockIdx.x >> 7;
  const int q0 = (blockIdx.x & 127) << 1;

  // stage raw scores (2 rows)
  {
    const int q = tid >> 7, j4 = (tid & 127) << 2;
    *(float4*)&sc[q][j4] = *(const float4*)&attn_io[(b * LQQ + q0 + q) * LKK + j4];
  }
  __syncthreads();

  // softmax: threads 0..127 -> q=0 (waves 0,1), 128..255 -> q=1
  const int q = tid >> 7, j = tid & 127;
  const int w2 = (tid >> 6) & 1;
  float x0 = sc[q][j], x1 = sc[q][j + 128], x2 = sc[q][j + 256], x3 = sc[q][j + 384];
  float mx = fmaxf(fmaxf(x0, x1), fmaxf(x2, x3));
#pragma unroll
  for (int off = 32; off; off >>= 1) mx = fmaxf(mx, __shfl_xor(mx, off));
  if ((tid & 63) == 0) redm[q][w2] = mx;
  __syncthreads();
  mx = fmaxf(redm[q][0], redm[q][1]);
  float p0 = fast_exp2((x0 - mx) * LOG2E);
  float p1 = fast_exp2((x1 - mx) * LOG2E);
  float p2 = fast_exp2((x2 - mx) * LOG2E);
  float p3 = fast_exp2((x3 - mx) * LOG2E);
  float sum = (p0 + p1) + (p2 + p3);
#pragma unroll
  for (int off = 32; off; off >>= 1) sum += __shfl_xor(sum, off);
  if ((tid & 63) == 0) reds[q][w2] = sum;
  __syncthreads();
  sum = reds[q][0] + reds[q][1];
  const float inv = fast_rcp(sum);
  p0 *= inv; p1 *= inv; p2 *= inv; p3 *= inv;
  const int arow = (b * LQQ + q0 + q) * LKK + j;
  attn_io[arow]       = p0;
  attn_io[arow + 128] = p1;
  attn_io[arow + 256] = p2;
  attn_io[arow + 384] = p3;
  sc[q][j]       = p0;
  sc[q][j + 128] = p1;
  sc[q][j + 256] = p2;
  sc[q][j + 384] = p3;
  __syncthreads();

  // context: thread = (k-quarter, float4 d); both q-rows; LDS reduce over 4 k-quarters
  {
    const int kh = tid >> 6, dv = (tid & 63) << 2;
    const int kb = kh << 7;          // 128-k range
    float4 c0 = make_float4(0.f, 0.f, 0.f, 0.f);
    float4 c1 = make_float4(0.f, 0.f, 0.f, 0.f);
    const float* __restrict__ vb = &value[(b * LKK + kb) * DD + dv];
    for (int s = 0; s < 128; s += 4) {
      const float4 p0v = *(const float4*)&sc[0][kb + s];
      const float4 p1v = *(const float4*)&sc[1][kb + s];
#pragma unroll
      for (int u = 0; u < 4; ++u) {
        const float4 vv = *(const float4*)vb; vb += DD;
        const float a0 = COMP(p0v, u), a1 = COMP(p1v, u);
        c0.x = fmaf(a0, vv.x, c0.x); c0.y = fmaf(a0, vv.y, c0.y);
        c0.z = fmaf(a0, vv.z, c0.z); c0.w = fmaf(a0, vv.w, c0.w);
        c1.x = fmaf(a1, vv.x, c1.x); c1.y = fmaf(a1, vv.y, c1.y);
        c1.z = fmaf(a1, vv.z, c1.z); c1.w = fmaf(a1, vv.w, c1.w);
      }
    }
    *(float4*)&scr[kh][0][dv] = c0;
    *(float4*)&scr[kh][1][dv] = c1;
  }
  __syncthreads();

  if (tid < 128) {
    const int qq = tid >> 6, d4 = (tid & 63) << 2;
    float4 s4 = make_float4(0.f, 0.f, 0.f, 0.f);
#pragma unroll
    for (int kh2 = 0; kh2 < 4; ++kh2) {
      const float4 rr = *(const float4*)&scr[kh2][qq][d4];
      s4.x += rr.x; s4.y += rr.y; s4.z += rr.z; s4.w += rr.w;
    }
    *(float4*)&ctx_out[(b * LQQ + q0 + qq) * DD + d4] = s4;
  }
}

extern "C" void kernel_launch(void* const* d_in, const int* in_sizes, int n_in,
                              void* d_out, int out_size, void* d_ws, size_t ws_size,
                              hipStream_t stream) {
  const float* query = (const float*)d_in[0];
  const float* key   = (const float*)d_in[1];
  const float* value = (const float*)d_in[2];
  const float* W1    = (const float*)d_in[3];
  const float* W2    = (const float*)d_in[4];
  const float* v     = (const float*)d_in[5];
  const int*   mask  = (const int*)d_in[6];

  float* out      = (float*)d_out;
  float* ctx_out  = out;                       // [B, LQ, D]
  float* attn_out = out + BB * LQQ * DD;       // [B, LQ, LK] (raw scores, then probs)

  float* EaT = (float*)d_ws;                   // [B][D][LK] = 2 MB
  float* Eb  = EaT + BB * DD * LKK;            // [B*LQ][D]  = 1 MB

  dim3 g1(BB * LKK / 32 + BB * LQQ / 32, DD / 64);   // (96, 4)
  gemm_expk2<<<g1, 256, 0, stream>>>(key, query, W1, W2, EaT, Eb);

  scores_k<<<1024, 256, 0, stream>>>(EaT, Eb, v, mask, attn_out);

  smax_ctx<<<512, 256, 0, stream>>>(value, attn_out, ctx_out);
}

// Round 8
// 60.774 us; speedup vs baseline: 1.6462x; 1.4314x over previous
//
#include <hip/hip_runtime.h>
#include <math.h>

#define DD  256
#define LKK 512
#define LQQ 256
#define BB  4

constexpr float TWO_LOG2E = 2.8853900817779268f;  // 2*log2(e)
constexpr float LOG2E     = 1.4426950408889634f;

__device__ __forceinline__ float fast_rcp(float x)  { return __builtin_amdgcn_rcpf(x); }
__device__ __forceinline__ float fast_exp2(float x) { return __builtin_amdgcn_exp2f(x); }

#define COMP(v,u) ((u)==0?(v).x:(u)==1?(v).y:(u)==2?(v).z:(v).w)

// EaT[b][e][k] = exp(2 * key[b,k,:] . W1[e,:])  (d-major / transposed)
// Eb [b*LQ+q][e] = exp(2 * query[b,q,:] . W2[e,:])  (row-major)
__global__ __launch_bounds__(256) void gemm_expk2(const float* __restrict__ key,
                                                  const float* __restrict__ query,
                                                  const float* __restrict__ W1,
                                                  const float* __restrict__ W2,
                                                  float* __restrict__ EaT,
                                                  float* __restrict__ Eb) {
  __shared__ float Xs[16][36];
  __shared__ float Ws[16][68];
  const int tid = threadIdx.x;
  const bool isK = blockIdx.x < (BB * LKK / 32);
  const float* __restrict__ X = isK ? key : query;
  const float* __restrict__ W = isK ? W1 : W2;
  const int m0 = (isK ? blockIdx.x : blockIdx.x - BB * LKK / 32) * 32;
  const int e0 = blockIdx.y * 64;

  const int r0 = (tid >> 4) << 1;   // 0..30
  const int c0 = (tid & 15) << 2;   // 0..60
  const int xr = tid >> 3, xc = (tid & 7) << 1;
  const int wr = tid >> 2, wc = (tid & 3) << 2;

  float2 xv = *(const float2*)&X[(m0 + xr) * DD + xc];
  float4 wv = *(const float4*)&W[(e0 + wr) * DD + wc];

  float acc[2][4] = {};
  for (int k0 = 0; k0 < DD; k0 += 16) {
    __syncthreads();
    Xs[xc][xr] = xv.x; Xs[xc + 1][xr] = xv.y;
    Ws[wc][wr] = wv.x; Ws[wc + 1][wr] = wv.y; Ws[wc + 2][wr] = wv.z; Ws[wc + 3][wr] = wv.w;
    __syncthreads();
    if (k0 + 16 < DD) {
      xv = *(const float2*)&X[(m0 + xr) * DD + k0 + 16 + xc];
      wv = *(const float4*)&W[(e0 + wr) * DD + k0 + 16 + wc];
    }
#pragma unroll
    for (int k = 0; k < 16; ++k) {
      const float2 a  = *(const float2*)&Xs[k][r0];
      const float4 bq = *(const float4*)&Ws[k][c0];
      acc[0][0] = fmaf(a.x, bq.x, acc[0][0]); acc[0][1] = fmaf(a.x, bq.y, acc[0][1]);
      acc[0][2] = fmaf(a.x, bq.z, acc[0][2]); acc[0][3] = fmaf(a.x, bq.w, acc[0][3]);
      acc[1][0] = fmaf(a.y, bq.x, acc[1][0]); acc[1][1] = fmaf(a.y, bq.y, acc[1][1]);
      acc[1][2] = fmaf(a.y, bq.z, acc[1][2]); acc[1][3] = fmaf(a.y, bq.w, acc[1][3]);
    }
  }
  if (isK) {
    const int b = m0 >> 9;
    const int kloc = (m0 & 511) + r0;
#pragma unroll
    for (int j = 0; j < 4; ++j) {
      float2 o;
      o.x = fast_exp2(acc[0][j] * TWO_LOG2E);
      o.y = fast_exp2(acc[1][j] * TWO_LOG2E);
      *(float2*)&EaT[b * (DD * LKK) + (e0 + c0 + j) * LKK + kloc] = o;
    }
  } else {
#pragma unroll
    for (int i = 0; i < 2; ++i) {
      float4 o;
      o.x = fast_exp2(acc[i][0] * TWO_LOG2E);
      o.y = fast_exp2(acc[i][1] * TWO_LOG2E);
      o.z = fast_exp2(acc[i][2] * TWO_LOG2E);
      o.w = fast_exp2(acc[i][3] * TWO_LOG2E);
      *(float4*)&Eb[(m0 + r0 + i) * DD + e0 + c0] = o;
    }
  }
}

// Kernel A: masked scaled scores -> Sws. Register-lean + hand-pipelined.
// 512 blocks x 256 thr. Block = (b, 2 q-rows); thread = 2 k columns, all 256 d.
// Eb/v reads are wave-uniform (scalarized by compiler) -> no LDS, no syncthreads.
__global__ __launch_bounds__(256) void scores_k(const float* __restrict__ EaT,
                                                const float* __restrict__ Eb,
                                                const float* __restrict__ vvec,
                                                const int* __restrict__ mask,
                                                float* __restrict__ Sws) {
  const int tid = threadIdx.x;
  const int bid = blockIdx.x;        // 0..511
  const int b  = bid >> 7;
  const int q0 = (bid & 127) << 1;
  const int k2 = tid << 1;           // 0..510

  const float* __restrict__ eb0 = &Eb[(b * LQQ + q0) * DD];
  const float* __restrict__ eb1 = eb0 + DD;

  // Sv = sum_d v[d] (uniform reads, scalar-cached)
  float Sv = 0.f;
#pragma unroll
  for (int d = 0; d < DD; d += 4) {
    const float4 vv = *(const float4*)&vvec[d];
    Sv += (vv.x + vv.y) + (vv.z + vv.w);
  }

  const float* __restrict__ ea = &EaT[b * (DD * LKK) + k2];
  float a00 = 0.f, a01 = 0.f, a10 = 0.f, a11 = 0.f;

  // prologue: chunk d=0 loads
  float2 c0 = *(const float2*)&ea[0 * LKK];
  float2 c1 = *(const float2*)&ea[1 * LKK];
  float2 c2 = *(const float2*)&ea[2 * LKK];
  float2 c3 = *(const float2*)&ea[3 * LKK];
  float4 ub0 = *(const float4*)&eb0[0];
  float4 ub1 = *(const float4*)&eb1[0];
  float4 uvv = *(const float4*)&vvec[0];

  for (int d = 0; d < DD - 4; d += 4) {
    // issue next chunk's loads first (latency hides under the 48 VALU ops below)
    const float2 n0 = *(const float2*)&ea[(d + 4) * LKK];
    const float2 n1 = *(const float2*)&ea[(d + 5) * LKK];
    const float2 n2 = *(const float2*)&ea[(d + 6) * LKK];
    const float2 n3 = *(const float2*)&ea[(d + 7) * LKK];
    const float4 nb0 = *(const float4*)&eb0[d + 4];
    const float4 nb1 = *(const float4*)&eb1[d + 4];
    const float4 nvv = *(const float4*)&vvec[d + 4];
#pragma unroll
    for (int u = 0; u < 4; ++u) {
      const float2 a = (u == 0) ? c0 : (u == 1) ? c1 : (u == 2) ? c2 : c3;
      const float bq0 = COMP(ub0, u), bq1 = COMP(ub1, u), vd = COMP(uvv, u);
      a00 = fmaf(vd, fast_rcp(fmaf(a.x, bq0, 1.f)), a00);
      a01 = fmaf(vd, fast_rcp(fmaf(a.y, bq0, 1.f)), a01);
      a10 = fmaf(vd, fast_rcp(fmaf(a.x, bq1, 1.f)), a10);
      a11 = fmaf(vd, fast_rcp(fmaf(a.y, bq1, 1.f)), a11);
    }
    c0 = n0; c1 = n1; c2 = n2; c3 = n3;
    ub0 = nb0; ub1 = nb1; uvv = nvv;
  }
  // epilogue: last chunk (d = 252)
#pragma unroll
  for (int u = 0; u < 4; ++u) {
    const float2 a = (u == 0) ? c0 : (u == 1) ? c1 : (u == 2) ? c2 : c3;
    const float bq0 = COMP(ub0, u), bq1 = COMP(ub1, u), vd = COMP(uvv, u);
    a00 = fmaf(vd, fast_rcp(fmaf(a.x, bq0, 1.f)), a00);
    a01 = fmaf(vd, fast_rcp(fmaf(a.y, bq0, 1.f)), a01);
    a10 = fmaf(vd, fast_rcp(fmaf(a.x, bq1, 1.f)), a10);
    a11 = fmaf(vd, fast_rcp(fmaf(a.y, bq1, 1.f)), a11);
  }

  const float inv_scale = 0.0625f;  // 1/sqrt(256)
  float2 s0, s1;
  s0.x = (Sv - 2.f * a00) * inv_scale;
  s0.y = (Sv - 2.f * a01) * inv_scale;
  s1.x = (Sv - 2.f * a10) * inv_scale;
  s1.y = (Sv - 2.f * a11) * inv_scale;
  const int row0 = (b * LQQ + q0) * LKK + k2;
  const int row1 = row0 + LKK;
  const int2 m0 = *(const int2*)&mask[row0];
  const int2 m1 = *(const int2*)&mask[row1];
  if (m0.x == 0) s0.x = -1e10f;
  if (m0.y == 0) s0.y = -1e10f;
  if (m1.x == 0) s1.x = -1e10f;
  if (m1.y == 0) s1.y = -1e10f;
  *(float2*)&Sws[row0] = s0;
  *(float2*)&Sws[row1] = s1;
}

// Kernel B: softmax + attention out + context. 512 blocks x 256 thr.
// Block = (b, 2 q-rows). attn_io holds raw scores on entry, probabilities on exit.
__global__ __launch_bounds__(256) void smax_ctx(const float* __restrict__ value,
                                                float* attn_io,
                                                float* __restrict__ ctx_out) {
  __shared__ float sc[2][LKK];       // 4 KB
  __shared__ float scr[4][2][DD];    // 8 KB
  __shared__ float redm[2][2], reds[2][2];
  const int tid = threadIdx.x;
  const int b  = blockIdx.x >> 7;
  const int q0 = (blockIdx.x & 127) << 1;

  // stage raw scores (2 rows)
  {
    const int q = tid >> 7, j4 = (tid & 127) << 2;
    *(float4*)&sc[q][j4] = *(const float4*)&attn_io[(b * LQQ + q0 + q) * LKK + j4];
  }
  __syncthreads();

  // softmax: threads 0..127 -> q=0 (waves 0,1), 128..255 -> q=1
  const int q = tid >> 7, j = tid & 127;
  const int w2 = (tid >> 6) & 1;
  float x0 = sc[q][j], x1 = sc[q][j + 128], x2 = sc[q][j + 256], x3 = sc[q][j + 384];
  float mx = fmaxf(fmaxf(x0, x1), fmaxf(x2, x3));
#pragma unroll
  for (int off = 32; off; off >>= 1) mx = fmaxf(mx, __shfl_xor(mx, off));
  if ((tid & 63) == 0) redm[q][w2] = mx;
  __syncthreads();
  mx = fmaxf(redm[q][0], redm[q][1]);
  float p0 = fast_exp2((x0 - mx) * LOG2E);
  float p1 = fast_exp2((x1 - mx) * LOG2E);
  float p2 = fast_exp2((x2 - mx) * LOG2E);
  float p3 = fast_exp2((x3 - mx) * LOG2E);
  float sum = (p0 + p1) + (p2 + p3);
#pragma unroll
  for (int off = 32; off; off >>= 1) sum += __shfl_xor(sum, off);
  if ((tid & 63) == 0) reds[q][w2] = sum;
  __syncthreads();
  sum = reds[q][0] + reds[q][1];
  const float inv = fast_rcp(sum);
  p0 *= inv; p1 *= inv; p2 *= inv; p3 *= inv;
  const int arow = (b * LQQ + q0 + q) * LKK + j;
  attn_io[arow]       = p0;
  attn_io[arow + 128] = p1;
  attn_io[arow + 256] = p2;
  attn_io[arow + 384] = p3;
  sc[q][j]       = p0;
  sc[q][j + 128] = p1;
  sc[q][j + 256] = p2;
  sc[q][j + 384] = p3;
  __syncthreads();

  // context: thread = (k-quarter, float4 d); both q-rows; LDS reduce over 4 k-quarters
  {
    const int kh = tid >> 6, dv = (tid & 63) << 2;
    const int kb = kh << 7;          // 128-k range
    float4 c0 = make_float4(0.f, 0.f, 0.f, 0.f);
    float4 c1 = make_float4(0.f, 0.f, 0.f, 0.f);
    const float* __restrict__ vb = &value[(b * LKK + kb) * DD + dv];
    for (int s = 0; s < 128; s += 4) {
      const float4 p0v = *(const float4*)&sc[0][kb + s];
      const float4 p1v = *(const float4*)&sc[1][kb + s];
#pragma unroll
      for (int u = 0; u < 4; ++u) {
        const float4 vv = *(const float4*)vb; vb += DD;
        const float a0 = COMP(p0v, u), a1 = COMP(p1v, u);
        c0.x = fmaf(a0, vv.x, c0.x); c0.y = fmaf(a0, vv.y, c0.y);
        c0.z = fmaf(a0, vv.z, c0.z); c0.w = fmaf(a0, vv.w, c0.w);
        c1.x = fmaf(a1, vv.x, c1.x); c1.y = fmaf(a1, vv.y, c1.y);
        c1.z = fmaf(a1, vv.z, c1.z); c1.w = fmaf(a1, vv.w, c1.w);
      }
    }
    *(float4*)&scr[kh][0][dv] = c0;
    *(float4*)&scr[kh][1][dv] = c1;
  }
  __syncthreads();

  if (tid < 128) {
    const int qq = tid >> 6, d4 = (tid & 63) << 2;
    float4 s4 = make_float4(0.f, 0.f, 0.f, 0.f);
#pragma unroll
    for (int kh2 = 0; kh2 < 4; ++kh2) {
      const float4 rr = *(const float4*)&scr[kh2][qq][d4];
      s4.x += rr.x; s4.y += rr.y; s4.z += rr.z; s4.w += rr.w;
    }
    *(float4*)&ctx_out[(b * LQQ + q0 + qq) * DD + d4] = s4;
  }
}

extern "C" void kernel_launch(void* const* d_in, const int* in_sizes, int n_in,
                              void* d_out, int out_size, void* d_ws, size_t ws_size,
                              hipStream_t stream) {
  const float* query = (const float*)d_in[0];
  const float* key   = (const float*)d_in[1];
  const float* value = (const float*)d_in[2];
  const float* W1    = (const float*)d_in[3];
  const float* W2    = (const float*)d_in[4];
  const float* v     = (const float*)d_in[5];
  const int*   mask  = (const int*)d_in[6];

  float* out      = (float*)d_out;
  float* ctx_out  = out;                       // [B, LQ, D]
  float* attn_out = out + BB * LQQ * DD;       // [B, LQ, LK] (raw scores, then probs)

  float* EaT = (float*)d_ws;                   // [B][D][LK] = 2 MB
  float* Eb  = EaT + BB * DD * LKK;            // [B*LQ][D]  = 1 MB

  dim3 g1(BB * LKK / 32 + BB * LQQ / 32, DD / 64);   // (96, 4)
  gemm_expk2<<<g1, 256, 0, stream>>>(key, query, W1, W2, EaT, Eb);

  scores_k<<<512, 256, 0, stream>>>(EaT, Eb, v, mask, attn_out);

  smax_ctx<<<512, 256, 0, stream>>>(value, attn_out, ctx_out);
}

// Round 9
// 54.177 us; speedup vs baseline: 1.8466x; 1.1218x over previous
//
#include <hip/hip_runtime.h>
#include <math.h>

#define DD  256
#define LKK 512
#define LQQ 256
#define BB  4

constexpr float TWO_LOG2E = 2.8853900817779268f;  // 2*log2(e)
constexpr float LOG2E     = 1.4426950408889634f;

__device__ __forceinline__ float fast_rcp(float x)  { return __builtin_amdgcn_rcpf(x); }
__device__ __forceinline__ float fast_exp2(float x) { return __builtin_amdgcn_exp2f(x); }

#define COMP(v,u) ((u)==0?(v).x:(u)==1?(v).y:(u)==2?(v).z:(v).w)

// EaT[b][e][k] = exp(2 * key[b,k,:] . W1[e,:])  (d-major / transposed)
// Eb [b*LQ+q][e] = exp(2 * query[b,q,:] . W2[e,:])  (row-major)
__global__ __launch_bounds__(256) void gemm_expk2(const float* __restrict__ key,
                                                  const float* __restrict__ query,
                                                  const float* __restrict__ W1,
                                                  const float* __restrict__ W2,
                                                  float* __restrict__ EaT,
                                                  float* __restrict__ Eb) {
  __shared__ float Xs[16][36];
  __shared__ float Ws[16][68];
  const int tid = threadIdx.x;
  const bool isK = blockIdx.x < (BB * LKK / 32);
  const float* __restrict__ X = isK ? key : query;
  const float* __restrict__ W = isK ? W1 : W2;
  const int m0 = (isK ? blockIdx.x : blockIdx.x - BB * LKK / 32) * 32;
  const int e0 = blockIdx.y * 64;

  const int r0 = (tid >> 4) << 1;   // 0..30
  const int c0 = (tid & 15) << 2;   // 0..60
  const int xr = tid >> 3, xc = (tid & 7) << 1;
  const int wr = tid >> 2, wc = (tid & 3) << 2;

  float2 xv = *(const float2*)&X[(m0 + xr) * DD + xc];
  float4 wv = *(const float4*)&W[(e0 + wr) * DD + wc];

  float acc[2][4] = {};
  for (int k0 = 0; k0 < DD; k0 += 16) {
    __syncthreads();
    Xs[xc][xr] = xv.x; Xs[xc + 1][xr] = xv.y;
    Ws[wc][wr] = wv.x; Ws[wc + 1][wr] = wv.y; Ws[wc + 2][wr] = wv.z; Ws[wc + 3][wr] = wv.w;
    __syncthreads();
    if (k0 + 16 < DD) {
      xv = *(const float2*)&X[(m0 + xr) * DD + k0 + 16 + xc];
      wv = *(const float4*)&W[(e0 + wr) * DD + k0 + 16 + wc];
    }
#pragma unroll
    for (int k = 0; k < 16; ++k) {
      const float2 a  = *(const float2*)&Xs[k][r0];
      const float4 bq = *(const float4*)&Ws[k][c0];
      acc[0][0] = fmaf(a.x, bq.x, acc[0][0]); acc[0][1] = fmaf(a.x, bq.y, acc[0][1]);
      acc[0][2] = fmaf(a.x, bq.z, acc[0][2]); acc[0][3] = fmaf(a.x, bq.w, acc[0][3]);
      acc[1][0] = fmaf(a.y, bq.x, acc[1][0]); acc[1][1] = fmaf(a.y, bq.y, acc[1][1]);
      acc[1][2] = fmaf(a.y, bq.z, acc[1][2]); acc[1][3] = fmaf(a.y, bq.w, acc[1][3]);
    }
  }
  if (isK) {
    const int b = m0 >> 9;
    const int kloc = (m0 & 511) + r0;
#pragma unroll
    for (int j = 0; j < 4; ++j) {
      float2 o;
      o.x = fast_exp2(acc[0][j] * TWO_LOG2E);
      o.y = fast_exp2(acc[1][j] * TWO_LOG2E);
      *(float2*)&EaT[b * (DD * LKK) + (e0 + c0 + j) * LKK + kloc] = o;
    }
  } else {
#pragma unroll
    for (int i = 0; i < 2; ++i) {
      float4 o;
      o.x = fast_exp2(acc[i][0] * TWO_LOG2E);
      o.y = fast_exp2(acc[i][1] * TWO_LOG2E);
      o.z = fast_exp2(acc[i][2] * TWO_LOG2E);
      o.w = fast_exp2(acc[i][3] * TWO_LOG2E);
      *(float4*)&Eb[(m0 + r0 + i) * DD + e0 + c0] = o;
    }
  }
}

// Fused: scores (register-lean, hand-pipelined) -> in-LDS softmax -> context.
// 512 blocks x 256 thr. Block = (b, 2 q-rows); phase-1 thread = 2 k-cols, all 256 d.
// Eb/v reads are wave-uniform (scalarized) -> phase 1 needs no LDS staging.
__global__ __launch_bounds__(256) void attn_fused(const float* __restrict__ EaT,
                                                  const float* __restrict__ Eb,
                                                  const float* __restrict__ vvec,
                                                  const float* __restrict__ value,
                                                  const int* __restrict__ mask,
                                                  float* __restrict__ ctx_out,
                                                  float* __restrict__ attn_out) {
  __shared__ float sc[2][LKK];       // 4 KB (scores, then probs)
  __shared__ float scr[4][2][DD];    // 8 KB (context k-partials)
  __shared__ float redm[2][2], reds[2][2];

  const int tid = threadIdx.x;
  const int bid = blockIdx.x;        // 0..511
  const int b  = bid >> 7;
  const int q0 = (bid & 127) << 1;
  const int k2 = tid << 1;           // 0..510

  const float* __restrict__ eb0 = &Eb[(b * LQQ + q0) * DD];
  const float* __restrict__ eb1 = eb0 + DD;

  // Sv = sum_d v[d] (uniform reads, scalar-cached)
  float Sv = 0.f;
#pragma unroll
  for (int d = 0; d < DD; d += 4) {
    const float4 vv = *(const float4*)&vvec[d];
    Sv += (vv.x + vv.y) + (vv.z + vv.w);
  }

  // ---- phase 1: scores for (2 k) x (2 q), pipelined over d-chunks of 4 ----
  {
    const float* __restrict__ ea = &EaT[b * (DD * LKK) + k2];
    float a00 = 0.f, a01 = 0.f, a10 = 0.f, a11 = 0.f;

    float2 c0 = *(const float2*)&ea[0 * LKK];
    float2 c1 = *(const float2*)&ea[1 * LKK];
    float2 c2 = *(const float2*)&ea[2 * LKK];
    float2 c3 = *(const float2*)&ea[3 * LKK];
    float4 ub0 = *(const float4*)&eb0[0];
    float4 ub1 = *(const float4*)&eb1[0];
    float4 uvv = *(const float4*)&vvec[0];

    for (int d = 0; d < DD - 4; d += 4) {
      const float2 n0 = *(const float2*)&ea[(d + 4) * LKK];
      const float2 n1 = *(const float2*)&ea[(d + 5) * LKK];
      const float2 n2 = *(const float2*)&ea[(d + 6) * LKK];
      const float2 n3 = *(const float2*)&ea[(d + 7) * LKK];
      const float4 nb0 = *(const float4*)&eb0[d + 4];
      const float4 nb1 = *(const float4*)&eb1[d + 4];
      const float4 nvv = *(const float4*)&vvec[d + 4];
#pragma unroll
      for (int u = 0; u < 4; ++u) {
        const float2 a = (u == 0) ? c0 : (u == 1) ? c1 : (u == 2) ? c2 : c3;
        const float bq0 = COMP(ub0, u), bq1 = COMP(ub1, u), vd = COMP(uvv, u);
        a00 = fmaf(vd, fast_rcp(fmaf(a.x, bq0, 1.f)), a00);
        a01 = fmaf(vd, fast_rcp(fmaf(a.y, bq0, 1.f)), a01);
        a10 = fmaf(vd, fast_rcp(fmaf(a.x, bq1, 1.f)), a10);
        a11 = fmaf(vd, fast_rcp(fmaf(a.y, bq1, 1.f)), a11);
      }
      c0 = n0; c1 = n1; c2 = n2; c3 = n3;
      ub0 = nb0; ub1 = nb1; uvv = nvv;
    }
#pragma unroll
    for (int u = 0; u < 4; ++u) {
      const float2 a = (u == 0) ? c0 : (u == 1) ? c1 : (u == 2) ? c2 : c3;
      const float bq0 = COMP(ub0, u), bq1 = COMP(ub1, u), vd = COMP(uvv, u);
      a00 = fmaf(vd, fast_rcp(fmaf(a.x, bq0, 1.f)), a00);
      a01 = fmaf(vd, fast_rcp(fmaf(a.y, bq0, 1.f)), a01);
      a10 = fmaf(vd, fast_rcp(fmaf(a.x, bq1, 1.f)), a10);
      a11 = fmaf(vd, fast_rcp(fmaf(a.y, bq1, 1.f)), a11);
    }

    const float inv_scale = 0.0625f;  // 1/sqrt(256)
    float2 s0, s1;
    s0.x = (Sv - 2.f * a00) * inv_scale;
    s0.y = (Sv - 2.f * a01) * inv_scale;
    s1.x = (Sv - 2.f * a10) * inv_scale;
    s1.y = (Sv - 2.f * a11) * inv_scale;
    const int row0 = (b * LQQ + q0) * LKK + k2;
    const int2 m0 = *(const int2*)&mask[row0];
    const int2 m1 = *(const int2*)&mask[row0 + LKK];
    if (m0.x == 0) s0.x = -1e10f;
    if (m0.y == 0) s0.y = -1e10f;
    if (m1.x == 0) s1.x = -1e10f;
    if (m1.y == 0) s1.y = -1e10f;
    *(float2*)&sc[0][k2] = s0;
    *(float2*)&sc[1][k2] = s1;
  }
  __syncthreads();

  // ---- phase 2: softmax (threads 0..127 -> q=0, 128..255 -> q=1) ----
  {
    const int q = tid >> 7, j = tid & 127;
    const int w2 = (tid >> 6) & 1;
    float x0 = sc[q][j], x1 = sc[q][j + 128], x2 = sc[q][j + 256], x3 = sc[q][j + 384];
    float mx = fmaxf(fmaxf(x0, x1), fmaxf(x2, x3));
#pragma unroll
    for (int off = 32; off; off >>= 1) mx = fmaxf(mx, __shfl_xor(mx, off));
    if ((tid & 63) == 0) redm[q][w2] = mx;
    __syncthreads();
    mx = fmaxf(redm[q][0], redm[q][1]);
    float p0 = fast_exp2((x0 - mx) * LOG2E);
    float p1 = fast_exp2((x1 - mx) * LOG2E);
    float p2 = fast_exp2((x2 - mx) * LOG2E);
    float p3 = fast_exp2((x3 - mx) * LOG2E);
    float sum = (p0 + p1) + (p2 + p3);
#pragma unroll
    for (int off = 32; off; off >>= 1) sum += __shfl_xor(sum, off);
    if ((tid & 63) == 0) reds[q][w2] = sum;
    __syncthreads();
    sum = reds[q][0] + reds[q][1];
    const float inv = fast_rcp(sum);
    p0 *= inv; p1 *= inv; p2 *= inv; p3 *= inv;
    const int arow = (b * LQQ + q0 + q) * LKK + j;
    attn_out[arow]       = p0;
    attn_out[arow + 128] = p1;
    attn_out[arow + 256] = p2;
    attn_out[arow + 384] = p3;
    sc[q][j]       = p0;
    sc[q][j + 128] = p1;
    sc[q][j + 256] = p2;
    sc[q][j + 384] = p3;
  }
  __syncthreads();

  // ---- phase 3: context (thread = k-quarter x float4 d, both q; LDS reduce) ----
  {
    const int kh = tid >> 6, dv = (tid & 63) << 2;
    const int kb = kh << 7;          // 128-k range
    float4 c0 = make_float4(0.f, 0.f, 0.f, 0.f);
    float4 c1 = make_float4(0.f, 0.f, 0.f, 0.f);
    const float* __restrict__ vb = &value[(b * LKK + kb) * DD + dv];
    for (int s = 0; s < 128; s += 4) {
      const float4 p0v = *(const float4*)&sc[0][kb + s];
      const float4 p1v = *(const float4*)&sc[1][kb + s];
#pragma unroll
      for (int u = 0; u < 4; ++u) {
        const float4 vv = *(const float4*)vb; vb += DD;
        const float a0 = COMP(p0v, u), a1 = COMP(p1v, u);
        c0.x = fmaf(a0, vv.x, c0.x); c0.y = fmaf(a0, vv.y, c0.y);
        c0.z = fmaf(a0, vv.z, c0.z); c0.w = fmaf(a0, vv.w, c0.w);
        c1.x = fmaf(a1, vv.x, c1.x); c1.y = fmaf(a1, vv.y, c1.y);
        c1.z = fmaf(a1, vv.z, c1.z); c1.w = fmaf(a1, vv.w, c1.w);
      }
    }
    *(float4*)&scr[kh][0][dv] = c0;
    *(float4*)&scr[kh][1][dv] = c1;
  }
  __syncthreads();

  if (tid < 128) {
    const int qq = tid >> 6, d4 = (tid & 63) << 2;
    float4 s4 = make_float4(0.f, 0.f, 0.f, 0.f);
#pragma unroll
    for (int kh2 = 0; kh2 < 4; ++kh2) {
      const float4 rr = *(const float4*)&scr[kh2][qq][d4];
      s4.x += rr.x; s4.y += rr.y; s4.z += rr.z; s4.w += rr.w;
    }
    *(float4*)&ctx_out[(b * LQQ + q0 + qq) * DD + d4] = s4;
  }
}

extern "C" void kernel_launch(void* const* d_in, const int* in_sizes, int n_in,
                              void* d_out, int out_size, void* d_ws, size_t ws_size,
                              hipStream_t stream) {
  const float* query = (const float*)d_in[0];
  const float* key   = (const float*)d_in[1];
  const float* value = (const float*)d_in[2];
  const float* W1    = (const float*)d_in[3];
  const float* W2    = (const float*)d_in[4];
  const float* v     = (const float*)d_in[5];
  const int*   mask  = (const int*)d_in[6];

  float* out      = (float*)d_out;
  float* ctx_out  = out;                       // [B, LQ, D]
  float* attn_out = out + BB * LQQ * DD;       // [B, LQ, LK]

  float* EaT = (float*)d_ws;                   // [B][D][LK] = 2 MB
  float* Eb  = EaT + BB * DD * LKK;            // [B*LQ][D]  = 1 MB

  dim3 g1(BB * LKK / 32 + BB * LQQ / 32, DD / 64);   // (96, 4)
  gemm_expk2<<<g1, 256, 0, stream>>>(key, query, W1, W2, EaT, Eb);

  attn_fused<<<512, 256, 0, stream>>>(EaT, Eb, v, value, mask, ctx_out, attn_out);
}